// Round 17
// baseline (303.381 us; speedup 1.0000x reference)
//
#include <hip/hip_runtime.h>

#define HDIM 96
#define LSTR 104   // LDS row stride in bf16 elems (96 + 8 pad); 208 B (16B-aligned rows)

typedef __attribute__((ext_vector_type(8))) short bf16x8;   // 8 bf16 = 4 VGPRs
typedef __attribute__((ext_vector_type(4))) float f32x4;

__device__ __forceinline__ unsigned short bf16rne(float x) {
  const unsigned u = __float_as_uint(x);
  return (unsigned short)((u + 0x7fff + ((u >> 16) & 1)) >> 16);
}

// fp32 -> (hi, lo) truncated bf16 pair; x ~= hi + lo with ~2^-16 rel error
__device__ __forceinline__ void split2(float x, unsigned short& hi, unsigned short& lo) {
  const unsigned u = __float_as_uint(x);
  hi = (unsigned short)(u >> 16);
  const float xhi = __uint_as_float(u & 0xffff0000u);
  lo = (unsigned short)(__float_as_uint(x - xhi) >> 16);
}

__global__ void zero_k(int* __restrict__ p, int n) {
  int i = blockIdx.x * blockDim.x + threadIdx.x;
  if (i < n) p[i] = 0;
}

__global__ void deg_rank_k(const int* __restrict__ dst, int* __restrict__ indeg,
                           int* __restrict__ rank, int e) {
  int i = blockIdx.x * blockDim.x + threadIdx.x;
  if (i < e) rank[i] = atomicAdd(&indeg[dst[i]], 1);
}

__device__ __forceinline__ int wave_incl_scan(int v, int lane) {
#pragma unroll
  for (int off = 1; off < 64; off <<= 1) {
    int t = __shfl_up(v, off, 64);
    if (lane >= off) v += t;
  }
  return v;
}

// Phase A (blocks [0,nb)): bsum[b] = chunk sum of indeg.
// Blocks [nb, ...): pre-split all 5 weight tiles into bf16 hi/lo, [n][k] layout.
__global__ __launch_bounds__(1024) void scan_a_split_k(
    const int* __restrict__ indeg, int* __restrict__ bsum, int n, int nb,
    const float* __restrict__ W0, const float* __restrict__ W1,
    const float* __restrict__ W2, const float* __restrict__ W3,
    unsigned short* __restrict__ dH, unsigned short* __restrict__ dL) {
  const int tid = threadIdx.x;
  if (blockIdx.x >= nb) {   // ---- split_w part ----
    const int t = (blockIdx.x - nb) * 1024 + tid;
    if (t < 5 * 9216) {
      const int tile = t / 9216, r = t % 9216;
      const int nn = r / 96, k = r % 96;
      const float* W = (tile == 0) ? W0 : (tile == 1) ? W1 : (tile == 2) ? W2 : W3;
      const int row = (tile == 4) ? 96 + k : k;
      unsigned short h, l;
      split2(W[row * 96 + nn], h, l);
      dH[t] = h;
      dL[t] = l;
    }
    return;
  }
  // ---- scan_a part ----
  __shared__ int ws[16];
  const int i = blockIdx.x * 1024 + tid;
  int v = (i < n) ? indeg[i] : 0;
#pragma unroll
  for (int off = 32; off; off >>= 1) v += __shfl_down(v, off, 64);
  if ((tid & 63) == 0) ws[tid >> 6] = v;
  __syncthreads();
  if (tid < 16) {
    int s = ws[tid];
#pragma unroll
    for (int off = 8; off; off >>= 1) s += __shfl_down(s, off, 16);
    if (tid == 0) bsum[blockIdx.x] = s;
  }
}

__global__ __launch_bounds__(1024) void scan_b_k(const int* __restrict__ bsum,
                                                 int* __restrict__ bbase,
                                                 int* __restrict__ offsets, int nb, int n) {
  __shared__ int ws[16];
  const int tid = threadIdx.x, lane = tid & 63, w = tid >> 6;
  const int v = (tid < nb) ? bsum[tid] : 0;
  int incl = wave_incl_scan(v, lane);
  if (lane == 63) ws[w] = incl;
  __syncthreads();
  if (tid < 16) {
    int s = ws[tid];
#pragma unroll
    for (int off = 1; off < 16; off <<= 1) {
      int t = __shfl_up(s, off, 16);
      if (tid >= off) s += t;
    }
    ws[tid] = s;
  }
  __syncthreads();
  incl += (w > 0 ? ws[w - 1] : 0);
  if (tid < nb) bbase[tid] = incl - v;
  if (tid == 0) offsets[n] = ws[15];
}

__global__ __launch_bounds__(1024) void scan_c_k(const int* __restrict__ indeg,
                                                 const int* __restrict__ bbase,
                                                 int* __restrict__ offsets,
                                                 float* __restrict__ dis, int n) {
  __shared__ int ws[16];
  const int tid = threadIdx.x, lane = tid & 63, w = tid >> 6;
  const int i = blockIdx.x * 1024 + tid;
  const int v = (i < n) ? indeg[i] : 0;
  int incl = wave_incl_scan(v, lane);
  if (lane == 63) ws[w] = incl;
  __syncthreads();
  if (tid < 16) {
    int s = ws[tid];
#pragma unroll
    for (int off = 1; off < 16; off <<= 1) {
      int t = __shfl_up(s, off, 16);
      if (tid >= off) s += t;
    }
    ws[tid] = s;
  }
  __syncthreads();
  incl += (w > 0 ? ws[w - 1] : 0);
  if (i < n) {
    offsets[i] = bbase[blockIdx.x] + incl - v;
    dis[i] = rsqrtf((float)(1 + v));
  }
}

// Blocks [0,pb): CSR placement. Blocks [pb,...): msgX = bf16(dis*x).
__global__ __launch_bounds__(256) void place_scale_k(
    const int* __restrict__ src, const int* __restrict__ dst,
    const int* __restrict__ rank, const int* __restrict__ offsets,
    int* __restrict__ csr_src, int e, int pb,
    const float* __restrict__ x, const float* __restrict__ dis,
    unsigned short* __restrict__ o, int n) {
  if (blockIdx.x < pb) {
    int i = blockIdx.x * 256 + threadIdx.x;
    if (i >= e) return;
    int d = dst[i];
    atomicExch(&csr_src[offsets[d] + rank[i]], src[i]);
  } else {
    int t = (blockIdx.x - pb) * 256 + threadIdx.x;
    if (t >= n * 24) return;
    const float d = dis[t / 24];
    float4 v = ((const float4*)x)[t];
    ushort4 h;
    h.x = bf16rne(v.x * d); h.y = bf16rne(v.y * d);
    h.z = bf16rne(v.z * d); h.w = bf16rne(v.w * d);
    ((ushort4*)o)[t] = h;
  }
}

__device__ __forceinline__ void acc8(float* a, uint4 p) {
  a[0] += __uint_as_float(p.x << 16);
  a[1] += __uint_as_float(p.x & 0xffff0000u);
  a[2] += __uint_as_float(p.y << 16);
  a[3] += __uint_as_float(p.y & 0xffff0000u);
  a[4] += __uint_as_float(p.z << 16);
  a[5] += __uint_as_float(p.z & 0xffff0000u);
  a[6] += __uint_as_float(p.w << 16);
  a[7] += __uint_as_float(p.w & 0xffff0000u);
}

// load one 4-edge stage: 12 uint4 (three 16B chunks per src row)
__device__ __forceinline__ void load_stage(const unsigned short* __restrict__ hp,
                                           const int* __restrict__ csr, int i,
                                           int qoff, uint4* b) {
  const int s0 = csr[i], s1 = csr[i + 1], s2 = csr[i + 2], s3 = csr[i + 3];
  const unsigned short* p0 = hp + (size_t)s0 * HDIM + qoff;
  const unsigned short* p1 = hp + (size_t)s1 * HDIM + qoff;
  const unsigned short* p2 = hp + (size_t)s2 * HDIM + qoff;
  const unsigned short* p3 = hp + (size_t)s3 * HDIM + qoff;
  b[0] = *(const uint4*)(p0); b[1] = *(const uint4*)(p0 + 32); b[2]  = *(const uint4*)(p0 + 64);
  b[3] = *(const uint4*)(p1); b[4] = *(const uint4*)(p1 + 32); b[5]  = *(const uint4*)(p1 + 64);
  b[6] = *(const uint4*)(p2); b[7] = *(const uint4*)(p2 + 32); b[8]  = *(const uint4*)(p2 + 64);
  b[9] = *(const uint4*)(p3); b[10] = *(const uint4*)(p3 + 32); b[11] = *(const uint4*)(p3 + 64);
}

__device__ __forceinline__ void acc_stage(float a[3][8], const uint4* b) {
  acc8(a[0], b[0]); acc8(a[1], b[1]); acc8(a[2], b[2]);
  acc8(a[0], b[3]); acc8(a[1], b[4]); acc8(a[2], b[5]);
  acc8(a[0], b[6]); acc8(a[1], b[7]); acc8(a[2], b[8]);
  acc8(a[0], b[9]); acc8(a[1], b[10]); acc8(a[2], b[11]);
}

// ---- fused gather + split-bf16 MFMA GEMM, 2-stage software-pipelined ----
// 64 nodes/block: each thread's fp32 gather accumulator IS its MFMA A-fragment
// (node=row0+16wv+m, k=32kc+8quad+j). Gather loop double-buffers 4-edge stages
// in registers: B's 12 loads issue BEFORE A is consumed, keeping ~12-24 vmem
// in flight continuously (R16's single-buffer sawtoothed 12->0 — latency-bound).
// LDS holds only W hi/lo (39.9 KB). min-3-waves bound guards against spill.
template<bool DUAL>
__global__ __launch_bounds__(256, 3) void gat_gemm_k(
    const int* __restrict__ csr_src, const int* __restrict__ offsets,
    const float* __restrict__ dis, const unsigned short* __restrict__ hp,
    const unsigned short* __restrict__ WH0, const unsigned short* __restrict__ WL0,
    const float* __restrict__ b0,
    const unsigned short* __restrict__ WH1, const unsigned short* __restrict__ WL1,
    const float* __restrict__ b1,
    unsigned short* __restrict__ outH, unsigned short* __restrict__ outL,
    unsigned short* __restrict__ outMsg, int M) {
  __shared__ __align__(16) unsigned short Wh[96 * LSTR], Wl[96 * LSTR];
  const int t = threadIdx.x;
  const int lane = t & 63, wv = t >> 6;
  const int m = lane & 15, quad = lane >> 4;
  const int qoff = 8 * quad;
  const int row0 = blockIdx.x * 64;
  const int node = row0 + 16 * wv + m;

  // stage W set0 (pure uint4 copies)
  for (int u = t; u < 1152; u += 256) {
    const int nn = u / 12, kq = u % 12;
    *(uint4*)(&Wh[nn * LSTR + 8 * kq]) = ((const uint4*)(WH0 + (size_t)nn * HDIM))[kq];
    *(uint4*)(&Wl[nn * LSTR + 8 * kq]) = ((const uint4*)(WL0 + (size_t)nn * HDIM))[kq];
  }

  // gather: a[kc][jj] accumulates k = 32*kc + 8*quad + jj  (== A-frag layout)
  float a[3][8];
#pragma unroll
  for (int c = 0; c < 3; c++)
#pragma unroll
    for (int jj = 0; jj < 8; jj++) a[c][jj] = 0.f;
  if (node < M) {
    const unsigned short* selfp = hp + (size_t)node * HDIM + qoff;
    acc8(a[0], *(const uint4*)(selfp));
    acc8(a[1], *(const uint4*)(selfp + 32));
    acc8(a[2], *(const uint4*)(selfp + 64));
    int i = offsets[node];
    const int end = offsets[node + 1];
    uint4 A[12], B[12];
    if (i + 4 <= end) {
      load_stage(hp, csr_src, i, qoff, A); i += 4;        // prologue
      while (i + 8 <= end) {                               // steady state: 2 stages
        load_stage(hp, csr_src, i, qoff, B);               // B in flight...
        acc_stage(a, A);                                   // ...while consuming A
        load_stage(hp, csr_src, i + 4, qoff, A);           // next A in flight...
        acc_stage(a, B);                                   // ...while consuming B
        i += 8;
      }
      if (i + 4 <= end) {                                  // one more full stage
        load_stage(hp, csr_src, i, qoff, B); i += 4;
        acc_stage(a, A);
        acc_stage(a, B);
      } else {
        acc_stage(a, A);
      }
    }
    for (; i < end; i++) {                                 // residual < 4 edges
      const unsigned short* p0 = hp + (size_t)csr_src[i] * HDIM + qoff;
      acc8(a[0], *(const uint4*)(p0));
      acc8(a[1], *(const uint4*)(p0 + 32));
      acc8(a[2], *(const uint4*)(p0 + 64));
    }
    const float dd = dis[node];
#pragma unroll
    for (int c = 0; c < 3; c++)
#pragma unroll
      for (int jj = 0; jj < 8; jj++) a[c][jj] *= dd;
  }
  // split to A fragments in registers
  bf16x8 ah[3], al[3];
#pragma unroll
  for (int c = 0; c < 3; c++)
#pragma unroll
    for (int jj = 0; jj < 8; jj++) {
      unsigned short h, l;
      split2(a[c][jj], h, l);
      ah[c][jj] = (short)h;
      al[c][jj] = (short)l;
    }

  __syncthreads();   // W set0 visible

  f32x4 acc0[6];
#pragma unroll
  for (int c = 0; c < 6; c++) acc0[c] = (f32x4){0.f, 0.f, 0.f, 0.f};
#pragma unroll
  for (int kc = 0; kc < 3; kc++) {
    const int ko = 32 * kc + qoff;
#pragma unroll
    for (int c = 0; c < 6; c++) {
      const bf16x8 wh = *(const bf16x8*)(&Wh[(16 * c + m) * LSTR + ko]);
      const bf16x8 wl = *(const bf16x8*)(&Wl[(16 * c + m) * LSTR + ko]);
      acc0[c] = __builtin_amdgcn_mfma_f32_16x16x32_bf16(ah[kc], wh, acc0[c], 0, 0, 0);
      acc0[c] = __builtin_amdgcn_mfma_f32_16x16x32_bf16(ah[kc], wl, acc0[c], 0, 0, 0);
      acc0[c] = __builtin_amdgcn_mfma_f32_16x16x32_bf16(al[kc], wh, acc0[c], 0, 0, 0);
    }
  }

  // epilogue set0: relu -> split pair.  D: col=16c+m, row = row0+16wv+4quad+r
  const int rbase = row0 + 16 * wv + 4 * quad;
#pragma unroll
  for (int c = 0; c < 6; c++) {
    const int col = 16 * c + m;
    const float bv = b0[col];
#pragma unroll
    for (int r = 0; r < 4; r++) {
      const int row = rbase + r;
      if (row < M) {
        const float v = fmaxf(acc0[c][r] + bv, 0.f);
        unsigned short h, l;
        split2(v, h, l);
        const size_t idx = (size_t)row * HDIM + col;
        outH[idx] = h;
        outL[idx] = l;
      }
    }
  }

  if (DUAL) {
    __syncthreads();   // all waves done reading W set0
    for (int u = t; u < 1152; u += 256) {
      const int nn = u / 12, kq = u % 12;
      *(uint4*)(&Wh[nn * LSTR + 8 * kq]) = ((const uint4*)(WH1 + (size_t)nn * HDIM))[kq];
      *(uint4*)(&Wl[nn * LSTR + 8 * kq]) = ((const uint4*)(WL1 + (size_t)nn * HDIM))[kq];
    }
    __syncthreads();
    f32x4 acc1[6];
#pragma unroll
    for (int c = 0; c < 6; c++) acc1[c] = (f32x4){0.f, 0.f, 0.f, 0.f};
#pragma unroll
    for (int kc = 0; kc < 3; kc++) {
      const int ko = 32 * kc + qoff;
#pragma unroll
      for (int c = 0; c < 6; c++) {
        const bf16x8 wh = *(const bf16x8*)(&Wh[(16 * c + m) * LSTR + ko]);
        const bf16x8 wl = *(const bf16x8*)(&Wl[(16 * c + m) * LSTR + ko]);
        acc1[c] = __builtin_amdgcn_mfma_f32_16x16x32_bf16(ah[kc], wh, acc1[c], 0, 0, 0);
        acc1[c] = __builtin_amdgcn_mfma_f32_16x16x32_bf16(ah[kc], wl, acc1[c], 0, 0, 0);
        acc1[c] = __builtin_amdgcn_mfma_f32_16x16x32_bf16(al[kc], wh, acc1[c], 0, 0, 0);
      }
    }
    float dv[4];
#pragma unroll
    for (int r = 0; r < 4; r++) dv[r] = (rbase + r < M) ? dis[rbase + r] : 0.f;
#pragma unroll
    for (int c = 0; c < 6; c++) {
      const int col = 16 * c + m;
      const float bv = b1[col];
#pragma unroll
      for (int r = 0; r < 4; r++) {
        const int row = rbase + r;
        if (row < M)
          outMsg[(size_t)row * HDIM + col] = bf16rne(fmaxf(acc1[c][r] + bv, 0.f) * dv[r]);
      }
    }
  }
}

// ---- concat GEMM (copy-only staging, pre-split A and W) ----
__global__ __launch_bounds__(256) void gemm_concat_k(
    const unsigned short* __restrict__ AH0, const unsigned short* __restrict__ AL0,
    const unsigned short* __restrict__ AH1, const unsigned short* __restrict__ AL1,
    const unsigned short* __restrict__ WH, const unsigned short* __restrict__ WL,
    const float* __restrict__ bias, float* __restrict__ out, int M) {
  __shared__ __align__(16) unsigned short Ah[64 * LSTR], Al[64 * LSTR];
  __shared__ __align__(16) unsigned short Wh[96 * LSTR], Wl[96 * LSTR];
  const int t = threadIdx.x;
  const int lane = t & 63, wv = t >> 6;
  const int m = lane & 15, quad = lane >> 4;
  const int row0 = blockIdx.x * 64;

  f32x4 acc[6];
#pragma unroll
  for (int c = 0; c < 6; c++) acc[c] = (f32x4){0.f, 0.f, 0.f, 0.f};

  for (int kt = 0; kt < 2; kt++) {
    const unsigned short* AH = kt ? AH1 : AH0;
    const unsigned short* AL = kt ? AL1 : AL0;
    if (kt) __syncthreads();
    for (int u = t; u < 768; u += 256) {
      const int r = u / 12, kq = u % 12;
      uint4 vh = make_uint4(0, 0, 0, 0), vl = make_uint4(0, 0, 0, 0);
      if (row0 + r < M) {
        vh = ((const uint4*)(AH + (size_t)(row0 + r) * HDIM))[kq];
        vl = ((const uint4*)(AL + (size_t)(row0 + r) * HDIM))[kq];
      }
      *(uint4*)(&Ah[r * LSTR + 8 * kq]) = vh;
      *(uint4*)(&Al[r * LSTR + 8 * kq]) = vl;
    }
    const unsigned short* WHt = WH + (size_t)kt * 9216;
    const unsigned short* WLt = WL + (size_t)kt * 9216;
    for (int u = t; u < 1152; u += 256) {
      const int nn = u / 12, kq = u % 12;
      *(uint4*)(&Wh[nn * LSTR + 8 * kq]) = ((const uint4*)(WHt + (size_t)nn * HDIM))[kq];
      *(uint4*)(&Wl[nn * LSTR + 8 * kq]) = ((const uint4*)(WLt + (size_t)nn * HDIM))[kq];
    }
    __syncthreads();
#pragma unroll
    for (int kc = 0; kc < 3; kc++) {
      const int ko = 32 * kc + 8 * quad;
      const bf16x8 ah = *(const bf16x8*)(&Ah[(16 * wv + m) * LSTR + ko]);
      const bf16x8 al = *(const bf16x8*)(&Al[(16 * wv + m) * LSTR + ko]);
#pragma unroll
      for (int c = 0; c < 6; c++) {
        const bf16x8 wh = *(const bf16x8*)(&Wh[(16 * c + m) * LSTR + ko]);
        const bf16x8 wl = *(const bf16x8*)(&Wl[(16 * c + m) * LSTR + ko]);
        acc[c] = __builtin_amdgcn_mfma_f32_16x16x32_bf16(ah, wh, acc[c], 0, 0, 0);
        acc[c] = __builtin_amdgcn_mfma_f32_16x16x32_bf16(ah, wl, acc[c], 0, 0, 0);
        acc[c] = __builtin_amdgcn_mfma_f32_16x16x32_bf16(al, wh, acc[c], 0, 0, 0);
      }
    }
  }

  const int rbase = row0 + 16 * wv + 4 * quad;
#pragma unroll
  for (int c = 0; c < 6; c++) {
    const int col = 16 * c + m;
    const float bv = bias[col];
#pragma unroll
    for (int r = 0; r < 4; r++) {
      const int row = rbase + r;
      if (row < M) out[(size_t)row * HDIM + col] = acc[c][r] + bv;
    }
  }
}

extern "C" void kernel_launch(void* const* d_in, const int* in_sizes, int n_in,
                              void* d_out, int out_size, void* d_ws, size_t ws_size,
                              hipStream_t stream) {
  const float* x       = (const float*)d_in[0];
  const int*   edge    = (const int*)d_in[1];
  const float* W_local = (const float*)d_in[2];
  const float* b_local = (const float*)d_in[3];
  const float* W_g1    = (const float*)d_in[4];
  const float* b_g1    = (const float*)d_in[5];
  const float* W_g2    = (const float*)d_in[6];
  const float* b_g2    = (const float*)d_in[7];
  const float* W_fuse  = (const float*)d_in[8]; // [192, 96] row-major
  const float* b_fuse  = (const float*)d_in[9];
  float* out = (float*)d_out;

  const int n = in_sizes[0] / HDIM;
  const int e = in_sizes[1] / 2;
  const int* src = edge;
  const int* dst = edge + e;
  const int nb = (n + 1023) / 1024;

  char* ws = (char*)d_ws;
  auto alloc = [&](size_t bytes) { char* p = ws; ws += (bytes + 255) & ~(size_t)255; return p; };
  int*   indeg   = (int*)alloc((size_t)n * 4);
  float* dis     = (float*)alloc((size_t)n * 4);
  int*   offsets = (int*)alloc((size_t)(n + 1) * 4);
  int*   bsum    = (int*)alloc((size_t)nb * 4);
  int*   bbase   = (int*)alloc((size_t)nb * 4);
  int*   rank    = (int*)alloc((size_t)e * 4);
  int*   csr_src = (int*)alloc((size_t)e * 4);
  const size_t mat16 = (size_t)n * HDIM * 2;
  unsigned short* msgX = (unsigned short*)alloc(mat16);   // x' messages
  unsigned short* msgG = (unsigned short*)alloc(mat16);   // g1' messages
  unsigned short* locH = (unsigned short*)alloc(mat16);   // local hi/lo
  unsigned short* locL = (unsigned short*)alloc(mat16);
  unsigned short* g2H  = (unsigned short*)alloc(mat16);   // g2 hi/lo
  unsigned short* g2L  = (unsigned short*)alloc(mat16);
  unsigned short* wH   = (unsigned short*)alloc(5 * 9216 * 2);
  unsigned short* wL   = (unsigned short*)alloc(5 * 9216 * 2);

  zero_k<<<(n + 255) / 256, 256, 0, stream>>>(indeg, n);
  deg_rank_k<<<(e + 255) / 256, 256, 0, stream>>>(dst, indeg, rank, e);
  // scan phase A + (independent) weight pre-split in one launch
  scan_a_split_k<<<nb + 45, 1024, 0, stream>>>(indeg, bsum, n, nb,
                                               W_local, W_g1, W_g2, W_fuse, wH, wL);
  scan_b_k<<<1, 1024, 0, stream>>>(bsum, bbase, offsets, nb, n);
  scan_c_k<<<nb, 1024, 0, stream>>>(indeg, bbase, offsets, dis, n);
  // CSR placement + x-message scaling in one launch (both depend on scan_c)
  const int pb = (e + 255) / 256;
  const int sb = (n * 24 + 255) / 256;
  place_scale_k<<<pb + sb, 256, 0, stream>>>(src, dst, rank, offsets, csr_src, e, pb,
                                             x, dis, msgX, n);

  const int gb = (n + 63) / 64;

  // hop 1 fused: gather(x') -> ax frags; local = split(relu(ax@Wl+b)); g1' = msg(dis·relu(ax@Wg1+b))
  gat_gemm_k<true><<<gb, 256, 0, stream>>>(csr_src, offsets, dis, msgX,
                                           wH, wL, b_local,
                                           wH + 9216, wL + 9216, b_g1,
                                           locH, locL, msgG, n);
  // hop 2 fused: gather(g1') -> ag2 frags; g2 = split(relu(ag2@Wg2+b))
  gat_gemm_k<false><<<gb, 256, 0, stream>>>(csr_src, offsets, dis, msgG,
                                            wH + 2 * 9216, wL + 2 * 9216, b_g2,
                                            nullptr, nullptr, nullptr,
                                            g2H, g2L, nullptr, n);
  // out = [local | g2] @ W_fuse + b_fuse
  gemm_concat_k<<<gb, 256, 0, stream>>>(locH, locL, g2H, g2L,
                                        wH + 3 * 9216, wL + 3 * 9216, b_fuse, out, n);
}

// Round 18
// 285.564 us; speedup vs baseline: 1.0624x; 1.0624x over previous
//
#include <hip/hip_runtime.h>

#define HDIM 96
#define LSTR 104   // LDS row stride in bf16 elems (96 + 8 pad); 208 B (16B-aligned rows)

typedef __attribute__((ext_vector_type(8))) short bf16x8;   // 8 bf16 = 4 VGPRs
typedef __attribute__((ext_vector_type(4))) float f32x4;

__device__ __forceinline__ unsigned short bf16rne(float x) {
  const unsigned u = __float_as_uint(x);
  return (unsigned short)((u + 0x7fff + ((u >> 16) & 1)) >> 16);
}

// fp32 -> (hi, lo) truncated bf16 pair; x ~= hi + lo with ~2^-16 rel error
__device__ __forceinline__ void split2(float x, unsigned short& hi, unsigned short& lo) {
  const unsigned u = __float_as_uint(x);
  hi = (unsigned short)(u >> 16);
  const float xhi = __uint_as_float(u & 0xffff0000u);
  lo = (unsigned short)(__float_as_uint(x - xhi) >> 16);
}

__global__ void zero_k(int* __restrict__ p, int n) {
  int i = blockIdx.x * blockDim.x + threadIdx.x;
  if (i < n) p[i] = 0;
}

__global__ void deg_rank_k(const int* __restrict__ dst, int* __restrict__ indeg,
                           int* __restrict__ rank, int e) {
  int i = blockIdx.x * blockDim.x + threadIdx.x;
  if (i < e) rank[i] = atomicAdd(&indeg[dst[i]], 1);
}

__device__ __forceinline__ int wave_incl_scan(int v, int lane) {
#pragma unroll
  for (int off = 1; off < 64; off <<= 1) {
    int t = __shfl_up(v, off, 64);
    if (lane >= off) v += t;
  }
  return v;
}

// Phase A (blocks [0,nb)): bsum[b] = chunk sum of indeg.
// Blocks [nb, ...): pre-split all 5 weight tiles into bf16 hi/lo, [n][k] layout.
__global__ __launch_bounds__(1024) void scan_a_split_k(
    const int* __restrict__ indeg, int* __restrict__ bsum, int n, int nb,
    const float* __restrict__ W0, const float* __restrict__ W1,
    const float* __restrict__ W2, const float* __restrict__ W3,
    unsigned short* __restrict__ dH, unsigned short* __restrict__ dL) {
  const int tid = threadIdx.x;
  if (blockIdx.x >= nb) {   // ---- split_w part ----
    const int t = (blockIdx.x - nb) * 1024 + tid;
    if (t < 5 * 9216) {
      const int tile = t / 9216, r = t % 9216;
      const int nn = r / 96, k = r % 96;
      const float* W = (tile == 0) ? W0 : (tile == 1) ? W1 : (tile == 2) ? W2 : W3;
      const int row = (tile == 4) ? 96 + k : k;
      unsigned short h, l;
      split2(W[row * 96 + nn], h, l);
      dH[t] = h;
      dL[t] = l;
    }
    return;
  }
  // ---- scan_a part ----
  __shared__ int ws[16];
  const int i = blockIdx.x * 1024 + tid;
  int v = (i < n) ? indeg[i] : 0;
#pragma unroll
  for (int off = 32; off; off >>= 1) v += __shfl_down(v, off, 64);
  if ((tid & 63) == 0) ws[tid >> 6] = v;
  __syncthreads();
  if (tid < 16) {
    int s = ws[tid];
#pragma unroll
    for (int off = 8; off; off >>= 1) s += __shfl_down(s, off, 16);
    if (tid == 0) bsum[blockIdx.x] = s;
  }
}

__global__ __launch_bounds__(1024) void scan_b_k(const int* __restrict__ bsum,
                                                 int* __restrict__ bbase,
                                                 int* __restrict__ offsets, int nb, int n) {
  __shared__ int ws[16];
  const int tid = threadIdx.x, lane = tid & 63, w = tid >> 6;
  const int v = (tid < nb) ? bsum[tid] : 0;
  int incl = wave_incl_scan(v, lane);
  if (lane == 63) ws[w] = incl;
  __syncthreads();
  if (tid < 16) {
    int s = ws[tid];
#pragma unroll
    for (int off = 1; off < 16; off <<= 1) {
      int t = __shfl_up(s, off, 16);
      if (tid >= off) s += t;
    }
    ws[tid] = s;
  }
  __syncthreads();
  incl += (w > 0 ? ws[w - 1] : 0);
  if (tid < nb) bbase[tid] = incl - v;
  if (tid == 0) offsets[n] = ws[15];
}

__global__ __launch_bounds__(1024) void scan_c_k(const int* __restrict__ indeg,
                                                 const int* __restrict__ bbase,
                                                 int* __restrict__ offsets,
                                                 float* __restrict__ dis, int n) {
  __shared__ int ws[16];
  const int tid = threadIdx.x, lane = tid & 63, w = tid >> 6;
  const int i = blockIdx.x * 1024 + tid;
  const int v = (i < n) ? indeg[i] : 0;
  int incl = wave_incl_scan(v, lane);
  if (lane == 63) ws[w] = incl;
  __syncthreads();
  if (tid < 16) {
    int s = ws[tid];
#pragma unroll
    for (int off = 1; off < 16; off <<= 1) {
      int t = __shfl_up(s, off, 16);
      if (tid >= off) s += t;
    }
    ws[tid] = s;
  }
  __syncthreads();
  incl += (w > 0 ? ws[w - 1] : 0);
  if (i < n) {
    offsets[i] = bbase[blockIdx.x] + incl - v;
    dis[i] = rsqrtf((float)(1 + v));
  }
}

// Blocks [0,pb): CSR placement. Blocks [pb,...): msgX = bf16(dis*x).
__global__ __launch_bounds__(256) void place_scale_k(
    const int* __restrict__ src, const int* __restrict__ dst,
    const int* __restrict__ rank, const int* __restrict__ offsets,
    int* __restrict__ csr_src, int e, int pb,
    const float* __restrict__ x, const float* __restrict__ dis,
    unsigned short* __restrict__ o, int n) {
  if (blockIdx.x < pb) {
    int i = blockIdx.x * 256 + threadIdx.x;
    if (i >= e) return;
    int d = dst[i];
    atomicExch(&csr_src[offsets[d] + rank[i]], src[i]);
  } else {
    int t = (blockIdx.x - pb) * 256 + threadIdx.x;
    if (t >= n * 24) return;
    const float d = dis[t / 24];
    float4 v = ((const float4*)x)[t];
    ushort4 h;
    h.x = bf16rne(v.x * d); h.y = bf16rne(v.y * d);
    h.z = bf16rne(v.z * d); h.w = bf16rne(v.w * d);
    ((ushort4*)o)[t] = h;
  }
}

__device__ __forceinline__ void acc8(float* a, uint4 p) {
  a[0] += __uint_as_float(p.x << 16);
  a[1] += __uint_as_float(p.x & 0xffff0000u);
  a[2] += __uint_as_float(p.y << 16);
  a[3] += __uint_as_float(p.y & 0xffff0000u);
  a[4] += __uint_as_float(p.z << 16);
  a[5] += __uint_as_float(p.z & 0xffff0000u);
  a[6] += __uint_as_float(p.w << 16);
  a[7] += __uint_as_float(p.w & 0xffff0000u);
}

// ---- fused gather + split-bf16 MFMA GEMM (R16 structure, unroll x6) ----
// 64 nodes/block: each thread's fp32 gather accumulator IS its MFMA A-fragment
// (node=row0+16wv+m, k=32kc+8quad+j). Main edge loop: issue all 18 uint4 loads
// (6 edges x 3 chunks) then accumulate — single-buffer, no cross-iteration
// liveness (R17's explicit double-buffer spilled to scratch: WRITE +21 MB).
// LDS holds only W hi/lo (39.9 KB).
template<bool DUAL>
__global__ __launch_bounds__(256) void gat_gemm_k(
    const int* __restrict__ csr_src, const int* __restrict__ offsets,
    const float* __restrict__ dis, const unsigned short* __restrict__ hp,
    const unsigned short* __restrict__ WH0, const unsigned short* __restrict__ WL0,
    const float* __restrict__ b0,
    const unsigned short* __restrict__ WH1, const unsigned short* __restrict__ WL1,
    const float* __restrict__ b1,
    unsigned short* __restrict__ outH, unsigned short* __restrict__ outL,
    unsigned short* __restrict__ outMsg, int M) {
  __shared__ __align__(16) unsigned short Wh[96 * LSTR], Wl[96 * LSTR];
  const int t = threadIdx.x;
  const int lane = t & 63, wv = t >> 6;
  const int m = lane & 15, quad = lane >> 4;
  const int qoff = 8 * quad;
  const int row0 = blockIdx.x * 64;
  const int node = row0 + 16 * wv + m;

  // stage W set0 (pure uint4 copies)
  for (int u = t; u < 1152; u += 256) {
    const int nn = u / 12, kq = u % 12;
    *(uint4*)(&Wh[nn * LSTR + 8 * kq]) = ((const uint4*)(WH0 + (size_t)nn * HDIM))[kq];
    *(uint4*)(&Wl[nn * LSTR + 8 * kq]) = ((const uint4*)(WL0 + (size_t)nn * HDIM))[kq];
  }

  // gather: a[kc][jj] accumulates k = 32*kc + 8*quad + jj  (== A-frag layout)
  float a[3][8];
#pragma unroll
  for (int c = 0; c < 3; c++)
#pragma unroll
    for (int jj = 0; jj < 8; jj++) a[c][jj] = 0.f;
  if (node < M) {
    const unsigned short* selfp = hp + (size_t)node * HDIM + qoff;
    acc8(a[0], *(const uint4*)(selfp));
    acc8(a[1], *(const uint4*)(selfp + 32));
    acc8(a[2], *(const uint4*)(selfp + 64));
    int i = offsets[node];
    const int end = offsets[node + 1];
    for (; i + 5 < end; i += 6) {
      const int s0 = csr_src[i],     s1 = csr_src[i + 1], s2 = csr_src[i + 2];
      const int s3 = csr_src[i + 3], s4 = csr_src[i + 4], s5 = csr_src[i + 5];
      const unsigned short* p0 = hp + (size_t)s0 * HDIM + qoff;
      const unsigned short* p1 = hp + (size_t)s1 * HDIM + qoff;
      const unsigned short* p2 = hp + (size_t)s2 * HDIM + qoff;
      const unsigned short* p3 = hp + (size_t)s3 * HDIM + qoff;
      const unsigned short* p4 = hp + (size_t)s4 * HDIM + qoff;
      const unsigned short* p5 = hp + (size_t)s5 * HDIM + qoff;
      // issue all 18 loads, then accumulate
      const uint4 v00 = *(const uint4*)(p0), v01 = *(const uint4*)(p0 + 32), v02 = *(const uint4*)(p0 + 64);
      const uint4 v10 = *(const uint4*)(p1), v11 = *(const uint4*)(p1 + 32), v12 = *(const uint4*)(p1 + 64);
      const uint4 v20 = *(const uint4*)(p2), v21 = *(const uint4*)(p2 + 32), v22 = *(const uint4*)(p2 + 64);
      const uint4 v30 = *(const uint4*)(p3), v31 = *(const uint4*)(p3 + 32), v32 = *(const uint4*)(p3 + 64);
      const uint4 v40 = *(const uint4*)(p4), v41 = *(const uint4*)(p4 + 32), v42 = *(const uint4*)(p4 + 64);
      const uint4 v50 = *(const uint4*)(p5), v51 = *(const uint4*)(p5 + 32), v52 = *(const uint4*)(p5 + 64);
      acc8(a[0], v00); acc8(a[1], v01); acc8(a[2], v02);
      acc8(a[0], v10); acc8(a[1], v11); acc8(a[2], v12);
      acc8(a[0], v20); acc8(a[1], v21); acc8(a[2], v22);
      acc8(a[0], v30); acc8(a[1], v31); acc8(a[2], v32);
      acc8(a[0], v40); acc8(a[1], v41); acc8(a[2], v42);
      acc8(a[0], v50); acc8(a[1], v51); acc8(a[2], v52);
    }
    if (i + 2 < end) {   // 3..5 residual: one 3-edge step
      const int s0 = csr_src[i], s1 = csr_src[i + 1], s2 = csr_src[i + 2];
      const unsigned short* p0 = hp + (size_t)s0 * HDIM + qoff;
      const unsigned short* p1 = hp + (size_t)s1 * HDIM + qoff;
      const unsigned short* p2 = hp + (size_t)s2 * HDIM + qoff;
      const uint4 v00 = *(const uint4*)(p0), v01 = *(const uint4*)(p0 + 32), v02 = *(const uint4*)(p0 + 64);
      const uint4 v10 = *(const uint4*)(p1), v11 = *(const uint4*)(p1 + 32), v12 = *(const uint4*)(p1 + 64);
      const uint4 v20 = *(const uint4*)(p2), v21 = *(const uint4*)(p2 + 32), v22 = *(const uint4*)(p2 + 64);
      acc8(a[0], v00); acc8(a[1], v01); acc8(a[2], v02);
      acc8(a[0], v10); acc8(a[1], v11); acc8(a[2], v12);
      acc8(a[0], v20); acc8(a[1], v21); acc8(a[2], v22);
      i += 3;
    }
    for (; i < end; i++) {
      const unsigned short* p0 = hp + (size_t)csr_src[i] * HDIM + qoff;
      acc8(a[0], *(const uint4*)(p0));
      acc8(a[1], *(const uint4*)(p0 + 32));
      acc8(a[2], *(const uint4*)(p0 + 64));
    }
    const float dd = dis[node];
#pragma unroll
    for (int c = 0; c < 3; c++)
#pragma unroll
      for (int jj = 0; jj < 8; jj++) a[c][jj] *= dd;
  }
  // split to A fragments in registers
  bf16x8 ah[3], al[3];
#pragma unroll
  for (int c = 0; c < 3; c++)
#pragma unroll
    for (int jj = 0; jj < 8; jj++) {
      unsigned short h, l;
      split2(a[c][jj], h, l);
      ah[c][jj] = (short)h;
      al[c][jj] = (short)l;
    }

  __syncthreads();   // W set0 visible

  f32x4 acc0[6];
#pragma unroll
  for (int c = 0; c < 6; c++) acc0[c] = (f32x4){0.f, 0.f, 0.f, 0.f};
#pragma unroll
  for (int kc = 0; kc < 3; kc++) {
    const int ko = 32 * kc + qoff;
#pragma unroll
    for (int c = 0; c < 6; c++) {
      const bf16x8 wh = *(const bf16x8*)(&Wh[(16 * c + m) * LSTR + ko]);
      const bf16x8 wl = *(const bf16x8*)(&Wl[(16 * c + m) * LSTR + ko]);
      acc0[c] = __builtin_amdgcn_mfma_f32_16x16x32_bf16(ah[kc], wh, acc0[c], 0, 0, 0);
      acc0[c] = __builtin_amdgcn_mfma_f32_16x16x32_bf16(ah[kc], wl, acc0[c], 0, 0, 0);
      acc0[c] = __builtin_amdgcn_mfma_f32_16x16x32_bf16(al[kc], wh, acc0[c], 0, 0, 0);
    }
  }

  // epilogue set0: relu -> split pair.  D: col=16c+m, row = row0+16wv+4quad+r
  const int rbase = row0 + 16 * wv + 4 * quad;
#pragma unroll
  for (int c = 0; c < 6; c++) {
    const int col = 16 * c + m;
    const float bv = b0[col];
#pragma unroll
    for (int r = 0; r < 4; r++) {
      const int row = rbase + r;
      if (row < M) {
        const float v = fmaxf(acc0[c][r] + bv, 0.f);
        unsigned short h, l;
        split2(v, h, l);
        const size_t idx = (size_t)row * HDIM + col;
        outH[idx] = h;
        outL[idx] = l;
      }
    }
  }

  if (DUAL) {
    __syncthreads();   // all waves done reading W set0
    for (int u = t; u < 1152; u += 256) {
      const int nn = u / 12, kq = u % 12;
      *(uint4*)(&Wh[nn * LSTR + 8 * kq]) = ((const uint4*)(WH1 + (size_t)nn * HDIM))[kq];
      *(uint4*)(&Wl[nn * LSTR + 8 * kq]) = ((const uint4*)(WL1 + (size_t)nn * HDIM))[kq];
    }
    __syncthreads();
    f32x4 acc1[6];
#pragma unroll
    for (int c = 0; c < 6; c++) acc1[c] = (f32x4){0.f, 0.f, 0.f, 0.f};
#pragma unroll
    for (int kc = 0; kc < 3; kc++) {
      const int ko = 32 * kc + qoff;
#pragma unroll
      for (int c = 0; c < 6; c++) {
        const bf16x8 wh = *(const bf16x8*)(&Wh[(16 * c + m) * LSTR + ko]);
        const bf16x8 wl = *(const bf16x8*)(&Wl[(16 * c + m) * LSTR + ko]);
        acc1[c] = __builtin_amdgcn_mfma_f32_16x16x32_bf16(ah[kc], wh, acc1[c], 0, 0, 0);
        acc1[c] = __builtin_amdgcn_mfma_f32_16x16x32_bf16(ah[kc], wl, acc1[c], 0, 0, 0);
        acc1[c] = __builtin_amdgcn_mfma_f32_16x16x32_bf16(al[kc], wh, acc1[c], 0, 0, 0);
      }
    }
    float dv[4];
#pragma unroll
    for (int r = 0; r < 4; r++) dv[r] = (rbase + r < M) ? dis[rbase + r] : 0.f;
#pragma unroll
    for (int c = 0; c < 6; c++) {
      const int col = 16 * c + m;
      const float bv = b1[col];
#pragma unroll
      for (int r = 0; r < 4; r++) {
        const int row = rbase + r;
        if (row < M)
          outMsg[(size_t)row * HDIM + col] = bf16rne(fmaxf(acc1[c][r] + bv, 0.f) * dv[r]);
      }
    }
  }
}

// ---- concat GEMM (copy-only staging, pre-split A and W) ----
__global__ __launch_bounds__(256) void gemm_concat_k(
    const unsigned short* __restrict__ AH0, const unsigned short* __restrict__ AL0,
    const unsigned short* __restrict__ AH1, const unsigned short* __restrict__ AL1,
    const unsigned short* __restrict__ WH, const unsigned short* __restrict__ WL,
    const float* __restrict__ bias, float* __restrict__ out, int M) {
  __shared__ __align__(16) unsigned short Ah[64 * LSTR], Al[64 * LSTR];
  __shared__ __align__(16) unsigned short Wh[96 * LSTR], Wl[96 * LSTR];
  const int t = threadIdx.x;
  const int lane = t & 63, wv = t >> 6;
  const int m = lane & 15, quad = lane >> 4;
  const int row0 = blockIdx.x * 64;

  f32x4 acc[6];
#pragma unroll
  for (int c = 0; c < 6; c++) acc[c] = (f32x4){0.f, 0.f, 0.f, 0.f};

  for (int kt = 0; kt < 2; kt++) {
    const unsigned short* AH = kt ? AH1 : AH0;
    const unsigned short* AL = kt ? AL1 : AL0;
    if (kt) __syncthreads();
    for (int u = t; u < 768; u += 256) {
      const int r = u / 12, kq = u % 12;
      uint4 vh = make_uint4(0, 0, 0, 0), vl = make_uint4(0, 0, 0, 0);
      if (row0 + r < M) {
        vh = ((const uint4*)(AH + (size_t)(row0 + r) * HDIM))[kq];
        vl = ((const uint4*)(AL + (size_t)(row0 + r) * HDIM))[kq];
      }
      *(uint4*)(&Ah[r * LSTR + 8 * kq]) = vh;
      *(uint4*)(&Al[r * LSTR + 8 * kq]) = vl;
    }
    const unsigned short* WHt = WH + (size_t)kt * 9216;
    const unsigned short* WLt = WL + (size_t)kt * 9216;
    for (int u = t; u < 1152; u += 256) {
      const int nn = u / 12, kq = u % 12;
      *(uint4*)(&Wh[nn * LSTR + 8 * kq]) = ((const uint4*)(WHt + (size_t)nn * HDIM))[kq];
      *(uint4*)(&Wl[nn * LSTR + 8 * kq]) = ((const uint4*)(WLt + (size_t)nn * HDIM))[kq];
    }
    __syncthreads();
#pragma unroll
    for (int kc = 0; kc < 3; kc++) {
      const int ko = 32 * kc + 8 * quad;
      const bf16x8 ah = *(const bf16x8*)(&Ah[(16 * wv + m) * LSTR + ko]);
      const bf16x8 al = *(const bf16x8*)(&Al[(16 * wv + m) * LSTR + ko]);
#pragma unroll
      for (int c = 0; c < 6; c++) {
        const bf16x8 wh = *(const bf16x8*)(&Wh[(16 * c + m) * LSTR + ko]);
        const bf16x8 wl = *(const bf16x8*)(&Wl[(16 * c + m) * LSTR + ko]);
        acc[c] = __builtin_amdgcn_mfma_f32_16x16x32_bf16(ah, wh, acc[c], 0, 0, 0);
        acc[c] = __builtin_amdgcn_mfma_f32_16x16x32_bf16(ah, wl, acc[c], 0, 0, 0);
        acc[c] = __builtin_amdgcn_mfma_f32_16x16x32_bf16(al, wh, acc[c], 0, 0, 0);
      }
    }
  }

  const int rbase = row0 + 16 * wv + 4 * quad;
#pragma unroll
  for (int c = 0; c < 6; c++) {
    const int col = 16 * c + m;
    const float bv = bias[col];
#pragma unroll
    for (int r = 0; r < 4; r++) {
      const int row = rbase + r;
      if (row < M) out[(size_t)row * HDIM + col] = acc[c][r] + bv;
    }
  }
}

extern "C" void kernel_launch(void* const* d_in, const int* in_sizes, int n_in,
                              void* d_out, int out_size, void* d_ws, size_t ws_size,
                              hipStream_t stream) {
  const float* x       = (const float*)d_in[0];
  const int*   edge    = (const int*)d_in[1];
  const float* W_local = (const float*)d_in[2];
  const float* b_local = (const float*)d_in[3];
  const float* W_g1    = (const float*)d_in[4];
  const float* b_g1    = (const float*)d_in[5];
  const float* W_g2    = (const float*)d_in[6];
  const float* b_g2    = (const float*)d_in[7];
  const float* W_fuse  = (const float*)d_in[8]; // [192, 96] row-major
  const float* b_fuse  = (const float*)d_in[9];
  float* out = (float*)d_out;

  const int n = in_sizes[0] / HDIM;
  const int e = in_sizes[1] / 2;
  const int* src = edge;
  const int* dst = edge + e;
  const int nb = (n + 1023) / 1024;

  char* ws = (char*)d_ws;
  auto alloc = [&](size_t bytes) { char* p = ws; ws += (bytes + 255) & ~(size_t)255; return p; };
  int*   indeg   = (int*)alloc((size_t)n * 4);
  float* dis     = (float*)alloc((size_t)n * 4);
  int*   offsets = (int*)alloc((size_t)(n + 1) * 4);
  int*   bsum    = (int*)alloc((size_t)nb * 4);
  int*   bbase   = (int*)alloc((size_t)nb * 4);
  int*   rank    = (int*)alloc((size_t)e * 4);
  int*   csr_src = (int*)alloc((size_t)e * 4);
  const size_t mat16 = (size_t)n * HDIM * 2;
  unsigned short* msgX = (unsigned short*)alloc(mat16);   // x' messages
  unsigned short* msgG = (unsigned short*)alloc(mat16);   // g1' messages
  unsigned short* locH = (unsigned short*)alloc(mat16);   // local hi/lo
  unsigned short* locL = (unsigned short*)alloc(mat16);
  unsigned short* g2H  = (unsigned short*)alloc(mat16);   // g2 hi/lo
  unsigned short* g2L  = (unsigned short*)alloc(mat16);
  unsigned short* wH   = (unsigned short*)alloc(5 * 9216 * 2);
  unsigned short* wL   = (unsigned short*)alloc(5 * 9216 * 2);

  zero_k<<<(n + 255) / 256, 256, 0, stream>>>(indeg, n);
  deg_rank_k<<<(e + 255) / 256, 256, 0, stream>>>(dst, indeg, rank, e);
  // scan phase A + (independent) weight pre-split in one launch
  scan_a_split_k<<<nb + 45, 1024, 0, stream>>>(indeg, bsum, n, nb,
                                               W_local, W_g1, W_g2, W_fuse, wH, wL);
  scan_b_k<<<1, 1024, 0, stream>>>(bsum, bbase, offsets, nb, n);
  scan_c_k<<<nb, 1024, 0, stream>>>(indeg, bbase, offsets, dis, n);
  // CSR placement + x-message scaling in one launch (both depend on scan_c)
  const int pb = (e + 255) / 256;
  const int sb = (n * 24 + 255) / 256;
  place_scale_k<<<pb + sb, 256, 0, stream>>>(src, dst, rank, offsets, csr_src, e, pb,
                                             x, dis, msgX, n);

  const int gb = (n + 63) / 64;

  // hop 1 fused: gather(x') -> ax frags; local = split(relu(ax@Wl+b)); g1' = msg(dis·relu(ax@Wg1+b))
  gat_gemm_k<true><<<gb, 256, 0, stream>>>(csr_src, offsets, dis, msgX,
                                           wH, wL, b_local,
                                           wH + 9216, wL + 9216, b_g1,
                                           locH, locL, msgG, n);
  // hop 2 fused: gather(g1') -> ag2 frags; g2 = split(relu(ag2@Wg2+b))
  gat_gemm_k<false><<<gb, 256, 0, stream>>>(csr_src, offsets, dis, msgG,
                                            wH + 2 * 9216, wL + 2 * 9216, b_g2,
                                            nullptr, nullptr, nullptr,
                                            g2H, g2L, nullptr, n);
  // out = [local | g2] @ W_fuse + b_fuse
  gemm_concat_k<<<gb, 256, 0, stream>>>(locH, locL, g2H, g2L,
                                        wH + 3 * 9216, wL + 3 * 9216, b_fuse, out, n);
}